// Round 2
// baseline (133.644 us; speedup 1.0000x reference)
//
#include <hip/hip_runtime.h>
#include <hip/hip_bf16.h>
#include <stdint.h>

#define DM 1024
#define NH 16
#define DH 64
#define BB 4
#define TT 1024
#define MR (BB*TT)

typedef __attribute__((ext_vector_type(8))) short bf16x8;
typedef __attribute__((ext_vector_type(4))) float f32x4;

typedef unsigned int __attribute__((address_space(1))) uint_g;
typedef unsigned int __attribute__((address_space(3))) uint_l;

static __device__ __forceinline__ void gload_lds16(const void* g, void* l) {
  __builtin_amdgcn_global_load_lds((const uint_g*)g, (uint_l*)l, 16, 0, 0);
}

static __device__ __forceinline__ void fence() { asm volatile("" ::: "memory"); }

static __device__ __forceinline__ unsigned short f2bf(float f) {
  union { float f; unsigned int u; } v; v.f = f;
  unsigned int r = v.u + 0x7fffu + ((v.u >> 16) & 1u);
  return (unsigned short)(r >> 16);
}
static __device__ __forceinline__ unsigned short f2bf_fast(float f) {
  union { float f; unsigned int u; } v; v.f = f;
  return (unsigned short)((v.u + 0x8000u) >> 16);   // P >= 0, finite: safe
}

__global__ __launch_bounds__(256) void k_cvt3(const float* __restrict__ x,
    const float* __restrict__ w1, const float* __restrict__ w2,
    unsigned short* __restrict__ xb, unsigned short* __restrict__ wqb,
    unsigned short* __restrict__ wob) {
  const int n1 = (MR * DM) / 4, n2 = (3 * DM * DM) / 4, n3 = (DM * DM) / 4;
  const int total = n1 + n2 + n3;
  for (int u = blockIdx.x * 256 + threadIdx.x; u < total; u += gridDim.x * 256) {
    const float* src; unsigned short* dst; int i;
    if (u < n1)           { src = x;  dst = xb;  i = u; }
    else if (u < n1 + n2) { src = w1; dst = wqb; i = u - n1; }
    else                  { src = w2; dst = wob; i = u - n1 - n2; }
    float4 v = reinterpret_cast<const float4*>(src)[i];
    ushort4 o;
    o.x = f2bf(v.x); o.y = f2bf(v.y); o.z = f2bf(v.z); o.w = f2bf(v.w);
    reinterpret_cast<ushort4*>(dst)[i] = o;
  }
}

// ---------------- 8-phase 256x256 GEMM: qkv = x @ Wqkv^T, scatter epilogue ----
// M=4096, N=3072, K=1024. 512 thr (8 waves, 2Mx4N), BK=64, 128KB LDS dbuf.
__global__ __launch_bounds__(512, 2) void k_gemm8(
    const unsigned short* __restrict__ A, const unsigned short* __restrict__ Bw,
    unsigned short* __restrict__ qb, unsigned short* __restrict__ kb,
    unsigned short* __restrict__ vtb) {
  __shared__ unsigned short lds[2][2][256 * 64];   // [buf][A/B][row][col] 128KB
  const int K = DM, nt = K / 64, ni = nt / 2;
  int tid = threadIdx.x, w = tid >> 6, l = tid & 63;
  int l15 = l & 15, k8 = l >> 4;
  int wm = w >> 2, wn = w & 3;
  int wg = blockIdx.x;                       // 192 wgs: bijective XCD swizzle
  int swz = (wg & 7) * 24 + (wg >> 3);
  int tm = swz / 12, tn = swz % 12;
  int m0 = tm << 8, n0 = tn << 8;
  int gc = (l & 7) ^ ((l >> 3) & 7);         // pre-swizzled source chunk
  int srow = l >> 3;

  f32x4 acc[8][4];
  #pragma unroll
  for (int i = 0; i < 8; ++i)
    #pragma unroll
    for (int j = 0; j < 4; ++j) acc[i][j] = (f32x4){0.f, 0.f, 0.f, 0.f};
  bf16x8 b[4][2];

  auto stA = [&](int buf, int h, int t) {
    #pragma unroll
    for (int q = 0; q < 2; ++q) {
      int seg = w + (q << 3);
      int R = (h << 7) + (seg << 3) + srow;
      gload_lds16(A + (size_t)(m0 + R) * K + (t << 6) + (gc << 3),
                  &lds[buf][0][((h << 7) + (seg << 3)) << 6]);
    }
  };
  auto stB = [&](int buf, int h, int t) {
    #pragma unroll
    for (int q = 0; q < 2; ++q) {
      int seg = w + (q << 3);
      int R = (h << 7) + (seg << 3) + srow;
      gload_lds16(Bw + (size_t)(n0 + R) * K + (t << 6) + (gc << 3),
                  &lds[buf][1][((h << 7) + (seg << 3)) << 6]);
    }
  };
  auto ldA = [&](int buf, int mf, int ks) -> bf16x8 {
    int R = (wm << 7) + (mf << 4) + l15;
    int ch = ((ks << 2) + k8) ^ (l15 & 7);
    return *(const bf16x8*)&lds[buf][0][(R << 6) + (ch << 3)];
  };
  auto ldB = [&](int buf, int nf, int ks) -> bf16x8 {
    int R = (wn << 6) + (nf << 4) + l15;
    int ch = ((ks << 2) + k8) ^ (l15 & 7);
    return *(const bf16x8*)&lds[buf][1][(R << 6) + (ch << 3)];
  };

#define GPH(BUF, Q, LOADB, STAGE, TAIL)                                        \
  {                                                                            \
    if (LOADB) {                                                               \
      _Pragma("unroll") for (int nf = 0; nf < 4; ++nf)                         \
          _Pragma("unroll") for (int ks = 0; ks < 2; ++ks)                     \
              b[nf][ks] = ldB(BUF, nf, ks);                                    \
    }                                                                          \
    bf16x8 a0k0 = ldA(BUF, 2 * Q, 0);                                          \
    bf16x8 a0k1 = ldA(BUF, 2 * Q, 1);                                          \
    bf16x8 a1k0 = ldA(BUF, 2 * Q + 1, 0);                                      \
    bf16x8 a1k1 = ldA(BUF, 2 * Q + 1, 1);                                      \
    STAGE;                                                                     \
    fence(); __builtin_amdgcn_s_barrier(); fence();                            \
    asm volatile("s_waitcnt lgkmcnt(0)" ::: "memory");                         \
    __builtin_amdgcn_sched_barrier(0);                                         \
    __builtin_amdgcn_s_setprio(1);                                             \
    _Pragma("unroll") for (int nf = 0; nf < 4; ++nf) {                         \
      acc[2 * Q][nf]     = __builtin_amdgcn_mfma_f32_16x16x32_bf16(a0k0, b[nf][0], acc[2 * Q][nf], 0, 0, 0);     \
      acc[2 * Q][nf]     = __builtin_amdgcn_mfma_f32_16x16x32_bf16(a0k1, b[nf][1], acc[2 * Q][nf], 0, 0, 0);     \
      acc[2 * Q + 1][nf] = __builtin_amdgcn_mfma_f32_16x16x32_bf16(a1k0, b[nf][0], acc[2 * Q + 1][nf], 0, 0, 0); \
      acc[2 * Q + 1][nf] = __builtin_amdgcn_mfma_f32_16x16x32_bf16(a1k1, b[nf][1], acc[2 * Q + 1][nf], 0, 0, 0); \
    }                                                                          \
    __builtin_amdgcn_s_setprio(0);                                             \
    TAIL;                                                                      \
    fence(); __builtin_amdgcn_s_barrier(); fence();                            \
  }

  // Prologue: A(0), B(0) -> buf0; B(1) -> buf1. A(1) comes at p0/p1 of iter 0.
  stA(0, 0, 0); stA(0, 1, 0);
  stB(0, 0, 0); stB(0, 1, 0);
  stB(1, 0, 1); stB(1, 1, 1);
  asm volatile("s_waitcnt vmcnt(4)" ::: "memory");   // A(0),B(0) landed; B(1) in flight
  fence(); __builtin_amdgcn_s_barrier(); fence();

  for (int i = 0; i < ni; ++i) {
    int t0 = 2 * i, t1 = t0 + 1;
    bool more = (t0 + 2 < nt);
    GPH(0, 0, true,  { stA(1, 0, t1); }, {});
    GPH(0, 1, false, { stA(1, 1, t1); }, {});
    GPH(0, 2, false, { if (more) stB(0, 0, t0 + 2); }, {});
    GPH(0, 3, false, { if (more) stB(0, 1, t0 + 2); },
        { if (more) { asm volatile("s_waitcnt vmcnt(4)" ::: "memory"); }
          else      { asm volatile("s_waitcnt vmcnt(0)" ::: "memory"); } });
    GPH(1, 0, true,  { if (more) stA(0, 0, t0 + 2); }, {});
    GPH(1, 1, false, { if (more) stA(0, 1, t0 + 2); }, {});
    GPH(1, 2, false, { if (more) stB(1, 0, t1 + 2); }, {});
    GPH(1, 3, false, { if (more) stB(1, 1, t1 + 2); },
        { if (more) { asm volatile("s_waitcnt vmcnt(4)" ::: "memory"); } });
  }
#undef GPH

  // Epilogue: scatter q (x1/8), k as [B,H,T,Dh], v as [B,H,Dh,T]
  #pragma unroll
  for (int mf = 0; mf < 8; ++mf) {
    #pragma unroll
    for (int nf = 0; nf < 4; ++nf) {
      int n = n0 + (wn << 6) + (nf << 4) + l15;
      int m_base = m0 + (wm << 7) + (mf << 4) + (k8 << 2);
      int s = n >> 10, rem = n & 1023;
      int h = rem >> 6, d = rem & 63;
      #pragma unroll
      for (int r = 0; r < 4; ++r) {
        int m = m_base + r;
        int bb = m >> 10, t = m & 1023;
        float v = acc[mf][nf][r];
        if (s == 0)
          qb[((size_t)(bb * NH + h) * TT + t) * DH + d] = f2bf(v * 0.125f);
        else if (s == 1)
          kb[((size_t)(bb * NH + h) * TT + t) * DH + d] = f2bf(v);
        else
          vtb[((size_t)(bb * NH + h) * DH + d) * TT + t] = f2bf(v);
      }
    }
  }
}

// ---------------- out-proj GEMM: 128x128, 2-phase dbuf, fp32 out -------------
__global__ __launch_bounds__(256) void k_gemm2(
    const unsigned short* __restrict__ A, const unsigned short* __restrict__ Bw,
    float* __restrict__ Of) {
  const int N = DM, K = DM;
  __shared__ unsigned short At[2][128 * 32];
  __shared__ unsigned short Bt[2][128 * 32];
  int tid = threadIdx.x, w = tid >> 6, l = tid & 63;
  int l15 = l & 15, k8 = l >> 4;
  int wg = blockIdx.x;                       // 256 wgs
  int swz = (wg & 7) * 32 + (wg >> 3);
  int tm = swz >> 3, tn = swz & 7;
  int m0 = tm << 7, n0 = tn << 7;

  f32x4 acc[4][4];
  #pragma unroll
  for (int i = 0; i < 4; ++i)
    #pragma unroll
    for (int j = 0; j < 4; ++j) acc[i][j] = (f32x4){0.f, 0.f, 0.f, 0.f};

  int srow = (w << 4) + (l >> 2);
  int sch = l & 3;
  int mrb = ((w >> 1) << 6) + l15;
  int nrb = ((w & 1) << 6) + l15;

  auto stage = [&](int buf, int kk) {
    #pragma unroll
    for (int p = 0; p < 2; ++p) {
      int row = srow + (p << 6);
      int c = sch ^ ((row >> 1) & 3);
      int seg = w + (p << 2);
      gload_lds16(A + (size_t)(m0 + row) * K + kk + (c << 3), &At[buf][seg << 9]);
      gload_lds16(Bw + (size_t)(n0 + row) * K + kk + (c << 3), &Bt[buf][seg << 9]);
    }
  };

  stage(0, 0);
  __syncthreads();
  int cur = 0;
  for (int kk = 0; kk < K; kk += 32) {
    if (kk + 32 < K) stage(cur ^ 1, kk + 32);
    bf16x8 a[4], b[4];
    #pragma unroll
    for (int mf = 0; mf < 4; ++mf) {
      int row = mrb + (mf << 4);
      a[mf] = *(const bf16x8*)&At[cur][(row << 5) + ((k8 ^ ((row >> 1) & 3)) << 3)];
    }
    #pragma unroll
    for (int nf = 0; nf < 4; ++nf) {
      int row = nrb + (nf << 4);
      b[nf] = *(const bf16x8*)&Bt[cur][(row << 5) + ((k8 ^ ((row >> 1) & 3)) << 3)];
    }
    #pragma unroll
    for (int mf = 0; mf < 4; ++mf)
      #pragma unroll
      for (int nf = 0; nf < 4; ++nf)
        acc[mf][nf] = __builtin_amdgcn_mfma_f32_16x16x32_bf16(a[mf], b[nf], acc[mf][nf], 0, 0, 0);
    __syncthreads();            // drains vmcnt(0) for the prefetch + barrier
    cur ^= 1;
  }

  #pragma unroll
  for (int mf = 0; mf < 4; ++mf)
    #pragma unroll
    for (int nf = 0; nf < 4; ++nf) {
      int n = n0 + ((w & 1) << 6) + (nf << 4) + l15;
      int m_base = m0 + ((w >> 1) << 6) + (mf << 4) + (k8 << 2);
      #pragma unroll
      for (int r = 0; r < 4; ++r)
        Of[(size_t)(m_base + r) * N + n] = acc[mf][nf][r];
    }
}

// ---------------- flash attention, 2-phase dbuf + defer-max ------------------
__global__ __launch_bounds__(256) void k_attn(
    const unsigned short* __restrict__ qb, const unsigned short* __restrict__ kb,
    const unsigned short* __restrict__ vtb, unsigned short* __restrict__ yb) {
  __shared__ unsigned short Kt[2][64 * 64];
  __shared__ unsigned short Vt[2][64 * 64];
  __shared__ unsigned short Pl[4][16][72];
  int tid = threadIdx.x, w = tid >> 6, l = tid & 63;
  int l15 = l & 15, k8 = l >> 4;
  int bh = blockIdx.x >> 4;
  int qt = blockIdx.x & 15;
  int q0 = qt << 6;
  const unsigned short* Kb = kb + (size_t)bh * TT * DH;
  const unsigned short* Vb = vtb + (size_t)bh * DH * TT;
  const unsigned short* Qb = qb + (size_t)bh * TT * DH;

  int qrow = q0 + (w << 4) + l15;
  bf16x8 qf[2];
  #pragma unroll
  for (int c = 0; c < 2; ++c)
    qf[c] = *(const bf16x8*)&Qb[(size_t)qrow * DH + (c << 5) + (k8 << 3)];

  f32x4 y[4];
  #pragma unroll
  for (int i = 0; i < 4; ++i) y[i] = (f32x4){0.f, 0.f, 0.f, 0.f};
  float mrow = -INFINITY, lrow = 0.f;

  int srow = (w << 3) + (l >> 3);
  int sch = l & 7;

  auto stage = [&](int buf, int j0) {
    #pragma unroll
    for (int p = 0; p < 2; ++p) {
      int row = srow + (p << 5);
      int c = sch ^ (row & 7);
      int seg = w + (p << 2);
      gload_lds16(Kb + (size_t)(j0 + row) * DH + (c << 3), &Kt[buf][seg << 9]);
      gload_lds16(Vb + (size_t)row * TT + j0 + (c << 3), &Vt[buf][seg << 9]);
    }
  };

  stage(0, 0);
  __syncthreads();
  int cur = 0;

  for (int j0 = 0; j0 <= q0; j0 += 64) {
    if (j0 + 64 <= q0) stage(cur ^ 1, j0 + 64);

    f32x4 s[4];
    #pragma unroll
    for (int f = 0; f < 4; ++f) s[f] = (f32x4){0.f, 0.f, 0.f, 0.f};
    #pragma unroll
    for (int c = 0; c < 2; ++c) {
      #pragma unroll
      for (int f = 0; f < 4; ++f) {
        int row = (f << 4) + l15;
        bf16x8 ak = *(const bf16x8*)&Kt[cur][(row << 6) + ((((c << 2) + k8) ^ (row & 7)) << 3)];
        s[f] = __builtin_amdgcn_mfma_f32_16x16x32_bf16(ak, qf[c], s[f], 0, 0, 0);
      }
    }

    if (j0 == q0) {
      #pragma unroll
      for (int f = 0; f < 4; ++f)
        #pragma unroll
        for (int r = 0; r < 4; ++r)
          if (j0 + (f << 4) + (k8 << 2) + r > qrow) s[f][r] = -INFINITY;
    }

    float pmax = -INFINITY;
    #pragma unroll
    for (int f = 0; f < 4; ++f)
      #pragma unroll
      for (int r = 0; r < 4; ++r) pmax = fmaxf(pmax, s[f][r]);
    pmax = fmaxf(pmax, __shfl_xor(pmax, 16, 64));
    pmax = fmaxf(pmax, __shfl_xor(pmax, 32, 64));

    bool skip = __all(pmax - mrow <= 8.0f);          // T13 defer-max
    float mnew = skip ? mrow : fmaxf(mrow, pmax);
    float psum = 0.f;
    #pragma unroll
    for (int f = 0; f < 4; ++f)
      #pragma unroll
      for (int r = 0; r < 4; ++r) {
        float p = __expf(s[f][r] - mnew);
        s[f][r] = p;
        psum += p;
      }
    psum += __shfl_xor(psum, 16, 64);
    psum += __shfl_xor(psum, 32, 64);
    if (!skip) {
      float alpha = __expf(mrow - mnew);
      lrow *= alpha;
      #pragma unroll
      for (int mf = 0; mf < 4; ++mf) y[mf] *= alpha;
      mrow = mnew;
    }
    lrow += psum;

    #pragma unroll
    for (int f = 0; f < 4; ++f) {
      ushort4 pk;
      pk.x = f2bf_fast(s[f][0]); pk.y = f2bf_fast(s[f][1]);
      pk.z = f2bf_fast(s[f][2]); pk.w = f2bf_fast(s[f][3]);
      *(ushort4*)&Pl[w][l15][(f << 4) + (k8 << 2)] = pk;
    }
    asm volatile("s_waitcnt lgkmcnt(0)" ::: "memory");
    __builtin_amdgcn_sched_barrier(0);

    #pragma unroll
    for (int c = 0; c < 2; ++c) {
      bf16x8 bp = *(const bf16x8*)&Pl[w][l15][(c << 5) + (k8 << 3)];
      #pragma unroll
      for (int mf = 0; mf < 4; ++mf) {
        int dr = (mf << 4) + l15;
        bf16x8 av = *(const bf16x8*)&Vt[cur][(dr << 6) + ((((c << 2) + k8) ^ (dr & 7)) << 3)];
        y[mf] = __builtin_amdgcn_mfma_f32_16x16x32_bf16(av, bp, y[mf], 0, 0, 0);
      }
    }

    __syncthreads();            // drains vmcnt(0) for prefetch + barrier
    cur ^= 1;
  }

  float inv = 1.f / lrow;
  int bb = bh >> 4, h = bh & 15;
  #pragma unroll
  for (int mf = 0; mf < 4; ++mf) {
    ushort4 o;
    o.x = f2bf(y[mf][0] * inv);
    o.y = f2bf(y[mf][1] * inv);
    o.z = f2bf(y[mf][2] * inv);
    o.w = f2bf(y[mf][3] * inv);
    *(ushort4*)&yb[((size_t)(bb * TT + qrow) << 10) + (h << 6) + (mf << 4) + (k8 << 2)] = o;
  }
}

extern "C" void kernel_launch(void* const* d_in, const int* in_sizes, int n_in,
                              void* d_out, int out_size, void* d_ws, size_t ws_size,
                              hipStream_t stream) {
  const float* x    = (const float*)d_in[0];
  const float* wqkv = (const float*)d_in[1];
  const float* wout = (const float*)d_in[2];
  char* ws = (char*)d_ws;
  unsigned short* xb  = (unsigned short*)(ws + (size_t)0);
  unsigned short* wqb = (unsigned short*)(ws + ((size_t)8  << 20));
  unsigned short* wob = (unsigned short*)(ws + ((size_t)14 << 20));
  unsigned short* qbv = (unsigned short*)(ws + ((size_t)16 << 20));
  unsigned short* kbv = (unsigned short*)(ws + ((size_t)24 << 20));
  unsigned short* vtb = (unsigned short*)(ws + ((size_t)32 << 20));
  unsigned short* yb  = (unsigned short*)(ws + ((size_t)40 << 20));

  k_cvt3<<<2048, 256, 0, stream>>>(x, wqkv, wout, xb, wqb, wob);
  k_gemm8<<<192, 512, 0, stream>>>(xb, wqb, qbv, kbv, vtb);
  k_attn<<<1024, 256, 0, stream>>>(qbv, kbv, vtb, yb);
  k_gemm2<<<256, 256, 0, stream>>>(yb, wob, (float*)d_out);
}

// Round 3
// 110.281 us; speedup vs baseline: 1.2118x; 1.2118x over previous
//
#include <hip/hip_runtime.h>
#include <hip/hip_bf16.h>
#include <stdint.h>

#define DM 1024
#define NH 16
#define DH 64
#define BB 4
#define TT 1024
#define MR (BB*TT)

typedef __attribute__((ext_vector_type(8))) short bf16x8;
typedef __attribute__((ext_vector_type(4))) float f32x4;

typedef unsigned int __attribute__((address_space(1))) uint_g;
typedef unsigned int __attribute__((address_space(3))) uint_l;

static __device__ __forceinline__ void gload_lds16(const void* g, void* l) {
  __builtin_amdgcn_global_load_lds((const uint_g*)g, (uint_l*)l, 16, 0, 0);
}

static __device__ __forceinline__ unsigned short f2bf(float f) {
  union { float f; unsigned int u; } v; v.f = f;
  unsigned int r = v.u + 0x7fffu + ((v.u >> 16) & 1u);
  return (unsigned short)(r >> 16);
}
static __device__ __forceinline__ unsigned short f2bf_fast(float f) {
  union { float f; unsigned int u; } v; v.f = f;
  return (unsigned short)((v.u + 0x8000u) >> 16);   // P >= 0, finite: safe
}

__global__ __launch_bounds__(256) void k_cvt3(const float* __restrict__ x,
    const float* __restrict__ w1, const float* __restrict__ w2,
    unsigned short* __restrict__ xb, unsigned short* __restrict__ wqb,
    unsigned short* __restrict__ wob) {
  const int n1 = (MR * DM) / 4, n2 = (3 * DM * DM) / 4, n3 = (DM * DM) / 4;
  const int total = n1 + n2 + n3;
  for (int u = blockIdx.x * 256 + threadIdx.x; u < total; u += gridDim.x * 256) {
    const float* src; unsigned short* dst; int i;
    if (u < n1)           { src = x;  dst = xb;  i = u; }
    else if (u < n1 + n2) { src = w1; dst = wqb; i = u - n1; }
    else                  { src = w2; dst = wob; i = u - n1 - n2; }
    float4 v = reinterpret_cast<const float4*>(src)[i];
    ushort4 o;
    o.x = f2bf(v.x); o.y = f2bf(v.y); o.z = f2bf(v.z); o.w = f2bf(v.w);
    reinterpret_cast<ushort4*>(dst)[i] = o;
  }
}

// C = A @ B^T. 128x128 tile, BK=32, 4 waves, minimum-2-phase double buffer.
// EPI=0: scatter q (x1/8), k [B,H,T,Dh], v^T [B,H,Dh,T].  EPI=1: fp32 C store.
template<int EPI>
__global__ __launch_bounds__(256) void k_gemm(
    const unsigned short* __restrict__ A, const unsigned short* __restrict__ Bw,
    float* __restrict__ Of, unsigned short* __restrict__ qb,
    unsigned short* __restrict__ kb, unsigned short* __restrict__ vtb,
    int N, int K, int tiles_n) {
  __shared__ unsigned short At[2][128 * 32];
  __shared__ unsigned short Bt[2][128 * 32];
  int tid = threadIdx.x;
  int w = tid >> 6, l = tid & 63;
  int l15 = l & 15, k8 = l >> 4;
  int nwg = gridDim.x;
  int cpx = nwg >> 3;                      // grid divisible by 8 (bijective XCD swizzle)
  int wg = blockIdx.x;
  int swz = (wg & 7) * cpx + (wg >> 3);
  int tm = swz / tiles_n, tn = swz % tiles_n;
  int m0 = tm << 7, n0 = tn << 7;

  f32x4 acc[4][4];
  #pragma unroll
  for (int i = 0; i < 4; ++i)
    #pragma unroll
    for (int j = 0; j < 4; ++j) acc[i][j] = (f32x4){0.f, 0.f, 0.f, 0.f};

  int srow = (w << 4) + (l >> 2);          // staging row, seg p=0
  int sch = l & 3;
  int mrb = ((w >> 1) << 6) + l15;
  int nrb = ((w & 1) << 6) + l15;

  auto stage = [&](int buf, int kk) {
    #pragma unroll
    for (int p = 0; p < 2; ++p) {
      int row = srow + (p << 6);
      int c = sch ^ ((row >> 1) & 3);      // pre-swizzled global source, linear LDS dest
      int seg = w + (p << 2);
      gload_lds16(A + (size_t)(m0 + row) * K + kk + (c << 3), &At[buf][seg << 9]);
      gload_lds16(Bw + (size_t)(n0 + row) * K + kk + (c << 3), &Bt[buf][seg << 9]);
    }
  };

  stage(0, 0);
  __syncthreads();
  int cur = 0;
  for (int kk = 0; kk < K; kk += 32) {
    if (kk + 32 < K) stage(cur ^ 1, kk + 32);   // prefetch overlaps with compute below
    bf16x8 a[4], b[4];
    #pragma unroll
    for (int mf = 0; mf < 4; ++mf) {
      int row = mrb + (mf << 4);
      a[mf] = *(const bf16x8*)&At[cur][(row << 5) + ((k8 ^ ((row >> 1) & 3)) << 3)];
    }
    #pragma unroll
    for (int nf = 0; nf < 4; ++nf) {
      int row = nrb + (nf << 4);
      b[nf] = *(const bf16x8*)&Bt[cur][(row << 5) + ((k8 ^ ((row >> 1) & 3)) << 3)];
    }
    #pragma unroll
    for (int mf = 0; mf < 4; ++mf)
      #pragma unroll
      for (int nf = 0; nf < 4; ++nf)
        acc[mf][nf] = __builtin_amdgcn_mfma_f32_16x16x32_bf16(a[mf], b[nf], acc[mf][nf], 0, 0, 0);
    __syncthreads();            // drains vmcnt(0) for the prefetch + barrier
    cur ^= 1;
  }

  #pragma unroll
  for (int mf = 0; mf < 4; ++mf) {
    #pragma unroll
    for (int nf = 0; nf < 4; ++nf) {
      int n = n0 + ((w & 1) << 6) + (nf << 4) + l15;
      int m_base = m0 + ((w >> 1) << 6) + (mf << 4) + (k8 << 2);
      if (EPI == 1) {
        #pragma unroll
        for (int r = 0; r < 4; ++r)
          Of[(size_t)(m_base + r) * N + n] = acc[mf][nf][r];
      } else {
        int s = n >> 10, rem = n & 1023;
        int h = rem >> 6, d = rem & 63;
        #pragma unroll
        for (int r = 0; r < 4; ++r) {
          int m = m_base + r;
          int bb = m >> 10, t = m & 1023;
          float v = acc[mf][nf][r];
          if (s == 0)
            qb[((size_t)(bb * NH + h) * TT + t) * DH + d] = f2bf(v * 0.125f);
          else if (s == 1)
            kb[((size_t)(bb * NH + h) * TT + t) * DH + d] = f2bf(v);
          else
            vtb[((size_t)(bb * NH + h) * DH + d) * TT + t] = f2bf(v);
        }
      }
    }
  }
}

// Flash attention: 8 waves, QBLK=128 (wave w owns rows q0+16w..+16), KVBLK=64,
// double-buffered K/V staging, swapped QK^T, defer-max.
__global__ __launch_bounds__(512) void k_attn(
    const unsigned short* __restrict__ qb, const unsigned short* __restrict__ kb,
    const unsigned short* __restrict__ vtb, unsigned short* __restrict__ yb) {
  __shared__ unsigned short Kt[2][64 * 64];
  __shared__ unsigned short Vt[2][64 * 64];
  __shared__ unsigned short Pl[8][16][72];
  int tid = threadIdx.x, w = tid >> 6, l = tid & 63;
  int l15 = l & 15, k8 = l >> 4;
  int bh = blockIdx.x >> 3;                 // 8 q-blocks of 128 rows
  int qt = blockIdx.x & 7;
  int q0 = qt << 7;
  const unsigned short* Kb = kb + (size_t)bh * TT * DH;
  const unsigned short* Vb = vtb + (size_t)bh * DH * TT;
  const unsigned short* Qb = qb + (size_t)bh * TT * DH;

  int qrow = q0 + (w << 4) + l15;
  bf16x8 qf[2];
  #pragma unroll
  for (int c = 0; c < 2; ++c)
    qf[c] = *(const bf16x8*)&Qb[(size_t)qrow * DH + (c << 5) + (k8 << 3)];

  f32x4 y[4];
  #pragma unroll
  for (int i = 0; i < 4; ++i) y[i] = (f32x4){0.f, 0.f, 0.f, 0.f};
  float mrow = -INFINITY, lrow = 0.f;

  int srow = l >> 3;                        // wave-local row 0..7
  int sch = l & 7;

  auto stage = [&](int buf, int j0) {
    int row = (w << 3) + srow;              // 0..63, 8 rows per wave
    int c = sch ^ (row & 7);
    gload_lds16(Kb + (size_t)(j0 + row) * DH + (c << 3), &Kt[buf][(w << 3) << 6]);
    gload_lds16(Vb + (size_t)row * TT + j0 + (c << 3), &Vt[buf][(w << 3) << 6]);
  };

  stage(0, 0);
  __syncthreads();
  int cur = 0;

  for (int j0 = 0; j0 < q0 + 128; j0 += 64) {
    if (j0 + 64 < q0 + 128) stage(cur ^ 1, j0 + 64);

    f32x4 s[4];
    #pragma unroll
    for (int f = 0; f < 4; ++f) s[f] = (f32x4){0.f, 0.f, 0.f, 0.f};
    #pragma unroll
    for (int c = 0; c < 2; ++c) {
      #pragma unroll
      for (int f = 0; f < 4; ++f) {
        int row = (f << 4) + l15;
        bf16x8 ak = *(const bf16x8*)&Kt[cur][(row << 6) + ((((c << 2) + k8) ^ (row & 7)) << 3)];
        s[f] = __builtin_amdgcn_mfma_f32_16x16x32_bf16(ak, qf[c], s[f], 0, 0, 0);
      }
    }

    if (j0 + 64 > q0 + (w << 4)) {          // diagonal band for this wave (uniform branch)
      #pragma unroll
      for (int f = 0; f < 4; ++f)
        #pragma unroll
        for (int r = 0; r < 4; ++r)
          if (j0 + (f << 4) + (k8 << 2) + r > qrow) s[f][r] = -INFINITY;
    }

    float pmax = -INFINITY;
    #pragma unroll
    for (int f = 0; f < 4; ++f)
      #pragma unroll
      for (int r = 0; r < 4; ++r) pmax = fmaxf(pmax, s[f][r]);
    pmax = fmaxf(pmax, __shfl_xor(pmax, 16, 64));
    pmax = fmaxf(pmax, __shfl_xor(pmax, 32, 64));

    bool skip = __all(pmax - mrow <= 8.0f);          // T13 defer-max
    float mnew = skip ? mrow : fmaxf(mrow, pmax);
    float psum = 0.f;
    #pragma unroll
    for (int f = 0; f < 4; ++f)
      #pragma unroll
      for (int r = 0; r < 4; ++r) {
        float p = __expf(s[f][r] - mnew);
        s[f][r] = p;
        psum += p;
      }
    psum += __shfl_xor(psum, 16, 64);
    psum += __shfl_xor(psum, 32, 64);
    if (!skip) {
      float alpha = __expf(mrow - mnew);
      lrow *= alpha;
      #pragma unroll
      for (int mf = 0; mf < 4; ++mf) y[mf] *= alpha;
      mrow = mnew;
    }
    lrow += psum;

    #pragma unroll
    for (int f = 0; f < 4; ++f) {
      ushort4 pk;
      pk.x = f2bf_fast(s[f][0]); pk.y = f2bf_fast(s[f][1]);
      pk.z = f2bf_fast(s[f][2]); pk.w = f2bf_fast(s[f][3]);
      *(ushort4*)&Pl[w][l15][(f << 4) + (k8 << 2)] = pk;
    }
    asm volatile("s_waitcnt lgkmcnt(0)" ::: "memory");
    __builtin_amdgcn_sched_barrier(0);

    #pragma unroll
    for (int c = 0; c < 2; ++c) {
      bf16x8 bp = *(const bf16x8*)&Pl[w][l15][(c << 5) + (k8 << 3)];
      #pragma unroll
      for (int mf = 0; mf < 4; ++mf) {
        int dr = (mf << 4) + l15;
        bf16x8 av = *(const bf16x8*)&Vt[cur][(dr << 6) + ((((c << 2) + k8) ^ (dr & 7)) << 3)];
        y[mf] = __builtin_amdgcn_mfma_f32_16x16x32_bf16(av, bp, y[mf], 0, 0, 0);
      }
    }

    __syncthreads();            // drains vmcnt(0) for prefetch + barrier
    cur ^= 1;
  }

  float inv = 1.f / lrow;
  int bb = bh >> 4, h = bh & 15;
  #pragma unroll
  for (int mf = 0; mf < 4; ++mf) {
    ushort4 o;
    o.x = f2bf(y[mf][0] * inv);
    o.y = f2bf(y[mf][1] * inv);
    o.z = f2bf(y[mf][2] * inv);
    o.w = f2bf(y[mf][3] * inv);
    *(ushort4*)&yb[((size_t)(bb * TT + qrow) << 10) + (h << 6) + (mf << 4) + (k8 << 2)] = o;
  }
}

extern "C" void kernel_launch(void* const* d_in, const int* in_sizes, int n_in,
                              void* d_out, int out_size, void* d_ws, size_t ws_size,
                              hipStream_t stream) {
  const float* x    = (const float*)d_in[0];
  const float* wqkv = (const float*)d_in[1];
  const float* wout = (const float*)d_in[2];
  char* ws = (char*)d_ws;
  unsigned short* xb  = (unsigned short*)(ws + (size_t)0);
  unsigned short* wqb = (unsigned short*)(ws + ((size_t)8  << 20));
  unsigned short* wob = (unsigned short*)(ws + ((size_t)14 << 20));
  unsigned short* qbv = (unsigned short*)(ws + ((size_t)16 << 20));
  unsigned short* kbv = (unsigned short*)(ws + ((size_t)24 << 20));
  unsigned short* vtb = (unsigned short*)(ws + ((size_t)32 << 20));
  unsigned short* yb  = (unsigned short*)(ws + ((size_t)40 << 20));

  k_cvt3<<<2048, 256, 0, stream>>>(x, wqkv, wout, xb, wqb, wob);
  k_gemm<0><<<768, 256, 0, stream>>>(xb, wqb, nullptr, qbv, kbv, vtb, 3 * DM, DM, 24);
  k_attn<<<512, 512, 0, stream>>>(qbv, kbv, vtb, yb);
  k_gemm<1><<<256, 256, 0, stream>>>(yb, wob, (float*)d_out, nullptr, nullptr, nullptr, DM, DM, 8);
}